// Round 4
// baseline (111.616 us; speedup 1.0000x reference)
//
#include <hip/hip_runtime.h>

// TweetRep: x (8,6,32,32,30) int32, embeddings (50000,64) f32 -> out (8,384,32,32) f32.
// 4 pixels per wave (16-lane groups, lane = 4 dims as float4).
// Round-4 structure: explicit two-pass with ONLINE softmax in pass B so no
// more than one gathered row is ever live -> ~56 VGPR -> 6-8 waves/SIMD to
// hide gather latency (round-3 was latency-bound at ~2 waves/SIMD: VALUBusy
// 38%, Occupancy 24%, FETCH at only 3.4 TB/s).

#define LTOK 30
#define NPIX (8 * 6 * 32 * 32)   // 49152
#define L2E  1.4426950408889634f

template <int CTRL>
__device__ __forceinline__ float dppadd(float v) {
    // v += dpp_permute(v), full row/bank masks; folds to v_add_f32_dpp
    int t = __builtin_amdgcn_update_dpp(0, __float_as_int(v), CTRL, 0xF, 0xF, true);
    return v + __int_as_float(t);
}

// sum across the 16-lane group (butterfly: xor1, xor2, mirror8, mirror16)
__device__ __forceinline__ float group16_sum(float p) {
    p = dppadd<0xB1>(p);    // quad_perm {1,0,3,2}
    p = dppadd<0x4E>(p);    // quad_perm {2,3,0,1}
    p = dppadd<0x141>(p);   // row_half_mirror
    p = dppadd<0x140>(p);   // row_mirror
    return p;
}

__global__ __launch_bounds__(256, 6) void tweetrep_kernel(
        const int* __restrict__ x, const float* __restrict__ emb,
        float* __restrict__ out)
{
    const int lane16 = threadIdx.x & 15;
    const int pix    = (blockIdx.x << 4) | (threadIdx.x >> 4);  // 16 pixels/block

    // ---- indices: 7x dwordx4 + 1x dwordx2, uniform within each 16-lane group
    const int* xp = x + pix * LTOK;
    int idx[LTOK];
#pragma unroll
    for (int l = 0; l < 28; l += 4) {
        int4 ii = *reinterpret_cast<const int4*>(xp + l);
        idx[l] = ii.x; idx[l + 1] = ii.y; idx[l + 2] = ii.z; idx[l + 3] = ii.w;
    }
    { int2 ii = *reinterpret_cast<const int2*>(xp + 28); idx[28] = ii.x; idx[29] = ii.y; }

    const int eoff = lane16 << 2;   // this lane's 4 dims

    // ---- pass A: V = sum of rows (only V stays live) ----
    float4 V = make_float4(0.f, 0.f, 0.f, 0.f);
#pragma unroll
    for (int l = 0; l < LTOK; ++l) {
        float4 w = *reinterpret_cast<const float4*>(
                       emb + ((size_t)idx[l] << 6) + eoff);
        V.x += w.x; V.y += w.y; V.z += w.z; V.w += w.w;
    }

    // ---- pass B: re-gather, fold each row into online softmax ----
    float4 acc = make_float4(0.f, 0.f, 0.f, 0.f);
    float  den = 0.f;
    float  m   = -3.0e38f;
#pragma unroll
    for (int l = 0; l < LTOK; ++l) {
        float4 w = *reinterpret_cast<const float4*>(
                       emb + ((size_t)idx[l] << 6) + eoff);
        float p = w.x * V.x;
        p = fmaf(w.y, V.y, p);
        p = fmaf(w.z, V.z, p);
        p = fmaf(w.w, V.w, p);
        p = group16_sum(p);                       // b_l, same in all 16 lanes

        const float mn = fmaxf(m, p);
        const float sc = __builtin_exp2f((m - mn) * L2E);  // 0 on first iter
        const float e  = __builtin_exp2f((p - mn) * L2E);
        acc.x = fmaf(acc.x, sc, e * w.x);
        acc.y = fmaf(acc.y, sc, e * w.y);
        acc.z = fmaf(acc.z, sc, e * w.z);
        acc.w = fmaf(acc.w, sc, e * w.w);
        den   = fmaf(den,   sc, e);
        m = mn;
    }
    const float inv = __builtin_amdgcn_rcpf(den);

    // ---- out[bt*64 + e][hw], e = 4*lane16 + j ----
    const int bt = pix >> 10, hw = pix & 1023;
    float* op = out + (((size_t)(bt * 64 + (lane16 << 2))) << 10) + hw;
    op[0]    = acc.x * inv;
    op[1024] = acc.y * inv;
    op[2048] = acc.z * inv;
    op[3072] = acc.w * inv;
}

extern "C" void kernel_launch(void* const* d_in, const int* in_sizes, int n_in,
                              void* d_out, int out_size, void* d_ws, size_t ws_size,
                              hipStream_t stream)
{
    const int*   x   = (const int*)d_in[0];
    const float* emb = (const float*)d_in[1];
    float*       out = (float*)d_out;

    const int blocks = NPIX / 16;   // 16 pixels per 256-thread block
    tweetrep_kernel<<<blocks, 256, 0, stream>>>(x, emb, out);
}

// Round 5
// 47.019 us; speedup vs baseline: 2.3739x; 2.3739x over previous
//
#include <hip/hip_runtime.h>

// TweetRep: x (8,6,32,32,30) int32, embeddings (50000,64) f32 -> out (8,384,32,32) f32.
// 4 pixels per wave (16-lane groups, lane = 4 dims as float4).
// Round-5: two-gather + chunked ONLINE softmax, with LOW natural register
// pressure (no idx[30] array - x is re-read per pass from L2; no
// launch_bounds VGPR cap - round 4's (256,6) forced 40 VGPRs and spilled
// idx to scratch: WRITE_SIZE 13.6->209 MB, dur 47->112 us).

#define LTOK 30
#define NPIX (8 * 6 * 32 * 32)   // 49152
#define L2E  1.4426950408889634f

template <int CTRL>
__device__ __forceinline__ float dppadd(float v) {
    int t = __builtin_amdgcn_update_dpp(0, __float_as_int(v), CTRL, 0xF, 0xF, true);
    return v + __int_as_float(t);
}

// sum across the 16-lane group (butterfly: xor1, xor2, mirror8, mirror16)
__device__ __forceinline__ float group16_sum(float p) {
    p = dppadd<0xB1>(p);    // quad_perm {1,0,3,2}
    p = dppadd<0x4E>(p);    // quad_perm {2,3,0,1}
    p = dppadd<0x141>(p);   // row_half_mirror
    p = dppadd<0x140>(p);   // row_mirror
    return p;
}

__device__ __forceinline__ float dot4_group(const float4& w, const float4& V) {
    float p = w.x * V.x;
    p = fmaf(w.y, V.y, p);
    p = fmaf(w.z, V.z, p);
    p = fmaf(w.w, V.w, p);
    return group16_sum(p);
}

__global__ __launch_bounds__(256) void tweetrep_kernel(
        const int* __restrict__ x, const float* __restrict__ emb,
        float* __restrict__ out)
{
    const int lane16 = threadIdx.x & 15;
    const int pix    = (blockIdx.x << 4) | (threadIdx.x >> 4);  // 16 pixels/block
    const int eoff   = lane16 << 2;                             // this lane's 4 dims
    const int*   xp   = x + pix * LTOK;
    const float* embl = emb + eoff;

    // ---- pass A: V = sum of the 30 rows (only V stays live) ----
    float4 V = make_float4(0.f, 0.f, 0.f, 0.f);
#pragma unroll
    for (int c = 0; c < 28; c += 4) {
        int4 ii = *reinterpret_cast<const int4*>(xp + c);
        float4 w0 = *reinterpret_cast<const float4*>(embl + ((size_t)ii.x << 6));
        float4 w1 = *reinterpret_cast<const float4*>(embl + ((size_t)ii.y << 6));
        float4 w2 = *reinterpret_cast<const float4*>(embl + ((size_t)ii.z << 6));
        float4 w3 = *reinterpret_cast<const float4*>(embl + ((size_t)ii.w << 6));
        V.x += w0.x + w1.x + w2.x + w3.x;
        V.y += w0.y + w1.y + w2.y + w3.y;
        V.z += w0.z + w1.z + w2.z + w3.z;
        V.w += w0.w + w1.w + w2.w + w3.w;
    }
    {
        int2 ii = *reinterpret_cast<const int2*>(xp + 28);
        float4 w0 = *reinterpret_cast<const float4*>(embl + ((size_t)ii.x << 6));
        float4 w1 = *reinterpret_cast<const float4*>(embl + ((size_t)ii.y << 6));
        V.x += w0.x + w1.x; V.y += w0.y + w1.y;
        V.z += w0.z + w1.z; V.w += w0.w + w1.w;
    }

    // ---- pass B: re-gather, chunk-of-4 online softmax ----
    float4 acc = make_float4(0.f, 0.f, 0.f, 0.f);
    float  den = 0.f;
    float  m   = -3.0e38f;
#pragma unroll
    for (int c = 0; c < 28; c += 4) {
        int4 ii = *reinterpret_cast<const int4*>(xp + c);
        float4 w0 = *reinterpret_cast<const float4*>(embl + ((size_t)ii.x << 6));
        float4 w1 = *reinterpret_cast<const float4*>(embl + ((size_t)ii.y << 6));
        float4 w2 = *reinterpret_cast<const float4*>(embl + ((size_t)ii.z << 6));
        float4 w3 = *reinterpret_cast<const float4*>(embl + ((size_t)ii.w << 6));
        float p0 = dot4_group(w0, V);
        float p1 = dot4_group(w1, V);
        float p2 = dot4_group(w2, V);
        float p3 = dot4_group(w3, V);

        const float pm = fmaxf(fmaxf(p0, p1), fmaxf(p2, p3));
        const float mn = fmaxf(m, pm);
        const float sc = __builtin_exp2f((m - mn) * L2E);   // 0 on first chunk
        m = mn;
        const float e0 = __builtin_exp2f((p0 - mn) * L2E);
        const float e1 = __builtin_exp2f((p1 - mn) * L2E);
        const float e2 = __builtin_exp2f((p2 - mn) * L2E);
        const float e3 = __builtin_exp2f((p3 - mn) * L2E);
        acc.x *= sc; acc.y *= sc; acc.z *= sc; acc.w *= sc; den *= sc;
        acc.x = fmaf(e0, w0.x, acc.x); acc.y = fmaf(e0, w0.y, acc.y);
        acc.z = fmaf(e0, w0.z, acc.z); acc.w = fmaf(e0, w0.w, acc.w);
        acc.x = fmaf(e1, w1.x, acc.x); acc.y = fmaf(e1, w1.y, acc.y);
        acc.z = fmaf(e1, w1.z, acc.z); acc.w = fmaf(e1, w1.w, acc.w);
        acc.x = fmaf(e2, w2.x, acc.x); acc.y = fmaf(e2, w2.y, acc.y);
        acc.z = fmaf(e2, w2.z, acc.z); acc.w = fmaf(e2, w2.w, acc.w);
        acc.x = fmaf(e3, w3.x, acc.x); acc.y = fmaf(e3, w3.y, acc.y);
        acc.z = fmaf(e3, w3.z, acc.z); acc.w = fmaf(e3, w3.w, acc.w);
        den += e0 + e1 + e2 + e3;
    }
    {
        int2 ii = *reinterpret_cast<const int2*>(xp + 28);
        float4 w0 = *reinterpret_cast<const float4*>(embl + ((size_t)ii.x << 6));
        float4 w1 = *reinterpret_cast<const float4*>(embl + ((size_t)ii.y << 6));
        float p0 = dot4_group(w0, V);
        float p1 = dot4_group(w1, V);
        const float pm = fmaxf(p0, p1);
        const float mn = fmaxf(m, pm);
        const float sc = __builtin_exp2f((m - mn) * L2E);
        const float e0 = __builtin_exp2f((p0 - mn) * L2E);
        const float e1 = __builtin_exp2f((p1 - mn) * L2E);
        acc.x *= sc; acc.y *= sc; acc.z *= sc; acc.w *= sc; den *= sc;
        acc.x = fmaf(e0, w0.x, acc.x); acc.y = fmaf(e0, w0.y, acc.y);
        acc.z = fmaf(e0, w0.z, acc.z); acc.w = fmaf(e0, w0.w, acc.w);
        acc.x = fmaf(e1, w1.x, acc.x); acc.y = fmaf(e1, w1.y, acc.y);
        acc.z = fmaf(e1, w1.z, acc.z); acc.w = fmaf(e1, w1.w, acc.w);
        den += e0 + e1;
    }
    const float inv = __builtin_amdgcn_rcpf(den);

    // ---- out[bt*64 + e][hw], e = 4*lane16 + j ----
    const int bt = pix >> 10, hw = pix & 1023;
    float* op = out + (((size_t)(bt * 64 + eoff)) << 10) + hw;
    op[0]    = acc.x * inv;
    op[1024] = acc.y * inv;
    op[2048] = acc.z * inv;
    op[3072] = acc.w * inv;
}

extern "C" void kernel_launch(void* const* d_in, const int* in_sizes, int n_in,
                              void* d_out, int out_size, void* d_ws, size_t ws_size,
                              hipStream_t stream)
{
    const int*   x   = (const int*)d_in[0];
    const float* emb = (const float*)d_in[1];
    float*       out = (float*)d_out;

    const int blocks = NPIX / 16;   // 16 pixels per 256-thread block
    tweetrep_kernel<<<blocks, 256, 0, stream>>>(x, emb, out);
}